// Round 1
// baseline (140.297 us; speedup 1.0000x reference)
//
#include <hip/hip_runtime.h>

// Problem constants (from reference):
//   X:          [8][512][4096] f32
//   gates:      [8][8]          f32
//   core_first: [8][1][8][8]    f32   (E, r=1, m0, p)
//   cores_mid:  [6][8][8][8][8] f32   (i, E, r, m, p)
//   core_last:  [8][8][8][1]    f32   (E, r, n3, 1)
//   out:        [8][512][4096]  f32
//
// Math: per batch b, out[b] = (X[b] · K_in[b]) · K_out[b] with
//   K_in[(m3,m2,m1,m0),p4] = sum_{p1,p2,p3} M0[m0,p1] M1[p1,m1,p2] M2[p2,m2,p3] M3[p3,m3,p4]
//   K_out[p4,(n0,n1,n2,n3)] = sum_{p5,p6,p7} M4[p4,n0,p5] M5[p5,n1,p6] M6[p6,n2,p7] M7[p7,n3]
// where Mi = sum_e gates[b,e] * core_i[e].

#define MC_     32          // m-chunks for the V reduction
#define MCHUNK_ 128         // 4096 / MC_

__global__ __launch_bounds__(256) void k_compose(
    const float* __restrict__ gates,
    const float* __restrict__ core_first,
    const float* __restrict__ cores_mid,
    const float* __restrict__ core_last,
    float* __restrict__ Kin,   // [8][4096][8]
    float* __restrict__ Kout)  // [8][8][4096]
{
  const int part = blockIdx.x;   // 0..7 : m3 slice for Kin, n0 slice for Kout
  const int b    = blockIdx.y;
  const int t    = threadIdx.x;

  __shared__ float g[8];
  __shared__ float mg[3200];                     // merged cores
  __shared__ __align__(16) float A2[512];        // [(m1,m0)][p2]
  __shared__ __align__(16) float A3[4096];       // [(m2,m1,m0)][p3]
  __shared__ __align__(16) float C2[512];        // [p6][(n2,n3)]
  __shared__ __align__(16) float C3[4096];       // [p5][(n1,n2,n3)]

  if (t < 8) g[t] = gates[b*8 + t];
  __syncthreads();

  // merged cores: mg[0:64]=M0 (m0*8+p), mg[64+i*512 ...]=M_{i+1} (r*64+m*8+p) for i=0..5,
  // mg[3136:3200]=M7 (r*8+n3)
  for (int idx = t; idx < 3200; idx += 256) {
    float acc = 0.f;
    if (idx < 64) {
      #pragma unroll
      for (int e = 0; e < 8; ++e) acc += g[e] * core_first[e*64 + idx];
    } else if (idx < 3136) {
      const int i = (idx - 64) >> 9;
      const int w = (idx - 64) & 511;
      #pragma unroll
      for (int e = 0; e < 8; ++e) acc += g[e] * cores_mid[(i*8 + e)*512 + w];
    } else {
      const int w = idx - 3136;
      #pragma unroll
      for (int e = 0; e < 8; ++e) acc += g[e] * core_last[e*64 + w];
    }
    mg[idx] = acc;
  }
  __syncthreads();

  const float* mg0 = mg;
  const float* mg1 = mg + 64;            // cores[1] = cores_mid[0]
  const float* mg2 = mg + 64 + 512;
  const float* mg3 = mg + 64 + 1024;
  const float* mg4 = mg + 64 + 1536;
  const float* mg5 = mg + 64 + 2048;
  const float* mg6 = mg + 64 + 2560;
  const float* mg7 = mg + 3136;

  // Phase 1: A2 (512) + C2 (512)
  for (int idx = t; idx < 1024; idx += 256) {
    if (idx < 512) {
      const int mm = idx >> 3, p2 = idx & 7;
      const int m1 = mm >> 3, m0 = mm & 7;
      float acc = 0.f;
      #pragma unroll
      for (int p1 = 0; p1 < 8; ++p1)
        acc += mg0[m0*8 + p1] * mg1[p1*64 + m1*8 + p2];
      A2[idx] = acc;
    } else {
      const int id = idx - 512;
      const int p6 = id >> 6, n2 = (id >> 3) & 7, n3 = id & 7;
      float acc = 0.f;
      #pragma unroll
      for (int p7 = 0; p7 < 8; ++p7)
        acc += mg6[p6*64 + n2*8 + p7] * mg7[p7*8 + n3];
      C2[id] = acc;
    }
  }
  __syncthreads();

  // Phase 2: A3 (4096) + C3 (4096)
  for (int idx = t; idx < 8192; idx += 256) {
    if (idx < 4096) {
      const int rest = idx >> 3, p3 = idx & 7;   // rest = m2*64 + m1*8 + m0
      const int m2 = rest >> 6, mm = rest & 63;
      float acc = 0.f;
      #pragma unroll
      for (int p2 = 0; p2 < 8; ++p2)
        acc += A2[mm*8 + p2] * mg2[p2*64 + m2*8 + p3];
      A3[idx] = acc;
    } else {
      const int id = idx - 4096;
      const int p5 = id >> 9, n1 = (id >> 6) & 7, nn = id & 63;
      float acc = 0.f;
      #pragma unroll
      for (int p6 = 0; p6 < 8; ++p6)
        acc += mg5[p5*64 + n1*8 + p6] * C2[p6*64 + nn];
      C3[id] = acc;
    }
  }
  __syncthreads();

  // Final: Kin rows with m3 = part; Kout columns with n0 = part
  {
    float* kb = Kin + b*32768 + part*4096;   // (part*512 + r)*8 + p4
    #pragma unroll
    for (int rr = 0; rr < 2; ++rr) {
      const int r = t*2 + rr;                // r = (m2,m1,m0) in [0,512)
      #pragma unroll
      for (int p4 = 0; p4 < 8; ++p4) {
        float acc = 0.f;
        #pragma unroll
        for (int p3 = 0; p3 < 8; ++p3)
          acc += A3[r*8 + p3] * mg3[p3*64 + part*8 + p4];
        kb[r*8 + p4] = acc;
      }
    }
    float* ob = Kout + b*32768 + part*512;   // p4*4096 + part*512 + j
    #pragma unroll
    for (int jj = 0; jj < 2; ++jj) {
      const int j = t*2 + jj;                // j = (n1,n2,n3) in [0,512)
      #pragma unroll
      for (int p4 = 0; p4 < 8; ++p4) {
        float acc = 0.f;
        #pragma unroll
        for (int p5 = 0; p5 < 8; ++p5)
          acc += mg4[p4*64 + part*8 + p5] * C3[p5*512 + j];
        ob[p4*4096 + j] = acc;
      }
    }
  }
}

// V partials: Vpart[b][mc][s][p] = sum_{m in chunk mc} X[b][s][m] * Kin[b][m][p]
__global__ __launch_bounds__(256) void k_vpart(
    const float* __restrict__ X,
    const float* __restrict__ Kin,
    float* __restrict__ Vpart)
{
  const int mc = blockIdx.x;   // 0..31
  const int sg = blockIdx.y;   // 0..1
  const int b  = blockIdx.z;   // 0..7
  const int t  = threadIdx.x;

  __shared__ __align__(16) float lk[MCHUNK_ * 8];   // K_in chunk, 4 KB
  ((float4*)lk)[t] = ((const float4*)(Kin + b*32768 + mc*(MCHUNK_*8)))[t];
  __syncthreads();

  const int s = sg*256 + t;
  const float4* xr = (const float4*)(X + (size_t)(b*512 + s)*4096 + mc*MCHUNK_);

  float acc[8];
  #pragma unroll
  for (int p = 0; p < 8; ++p) acc[p] = 0.f;

  #pragma unroll 8
  for (int j = 0; j < MCHUNK_/4; ++j) {
    const float4 x4 = xr[j];
    const float* kp = &lk[j*32];
    #pragma unroll
    for (int p = 0; p < 8; ++p) acc[p] += x4.x * kp[p];
    #pragma unroll
    for (int p = 0; p < 8; ++p) acc[p] += x4.y * kp[8 + p];
    #pragma unroll
    for (int p = 0; p < 8; ++p) acc[p] += x4.z * kp[16 + p];
    #pragma unroll
    for (int p = 0; p < 8; ++p) acc[p] += x4.w * kp[24 + p];
  }

  float* vp = Vpart + ((size_t)(b*MC_ + mc)*512 + s)*8;
  *(float4*)(vp)     = make_float4(acc[0], acc[1], acc[2], acc[3]);
  *(float4*)(vp + 4) = make_float4(acc[4], acc[5], acc[6], acc[7]);
}

// out[b][s][n] = sum_p (sum_mc Vpart[b][mc][s][p]) * Kout[b][p][n]
__global__ __launch_bounds__(256) void k_out(
    const float* __restrict__ Vpart,
    const float* __restrict__ Kout,
    float* __restrict__ Out)
{
  const int nc = blockIdx.x;   // 0..3   (1024 n each)
  const int sg = blockIdx.y;   // 0..15  (32 s each)
  const int b  = blockIdx.z;   // 0..7
  const int t  = threadIdx.x;

  __shared__ __align__(16) float vs[32*8];

  // Sum the 32 m-chunk partials for this block's 32 s.  t == s_local*8 + p.
  {
    const float* vp = Vpart + ((size_t)b*MC_*512 + sg*32)*8 + t;
    float a = 0.f;
    #pragma unroll 8
    for (int mc = 0; mc < MC_; ++mc) a += vp[(size_t)mc*512*8];
    vs[t] = a;
  }

  // This thread's 4 output columns of K_out, all 8 rank rows, in registers.
  float4 kr[8];
  {
    const float* kb = Kout + b*32768 + nc*1024 + t*4;
    #pragma unroll
    for (int p = 0; p < 8; ++p) kr[p] = *(const float4*)(kb + p*4096);
  }
  __syncthreads();

  float* ob = Out + (size_t)(b*512 + sg*32)*4096 + nc*1024 + t*4;
  for (int s = 0; s < 32; ++s) {
    const float* vv = &vs[s*8];
    float o0 = 0.f, o1 = 0.f, o2 = 0.f, o3 = 0.f;
    #pragma unroll
    for (int p = 0; p < 8; ++p) {
      const float v = vv[p];
      o0 += v * kr[p].x; o1 += v * kr[p].y; o2 += v * kr[p].z; o3 += v * kr[p].w;
    }
    *(float4*)(ob + (size_t)s*4096) = make_float4(o0, o1, o2, o3);
  }
}

extern "C" void kernel_launch(void* const* d_in, const int* in_sizes, int n_in,
                              void* d_out, int out_size, void* d_ws, size_t ws_size,
                              hipStream_t stream) {
  const float* X     = (const float*)d_in[0];
  const float* gates = (const float*)d_in[1];
  const float* cf    = (const float*)d_in[2];
  const float* cm    = (const float*)d_in[3];
  const float* cl    = (const float*)d_in[4];
  float* out = (float*)d_out;

  float* ws    = (float*)d_ws;
  float* Kin   = ws;                 //  262144 floats (1 MB)
  float* Kout  = ws + 262144;        //  262144 floats (1 MB)
  float* Vpart = ws + 524288;        // 1048576 floats (4 MB)

  k_compose<<<dim3(8, 8),        256, 0, stream>>>(gates, cf, cm, cl, Kin, Kout);
  k_vpart <<<dim3(MC_, 2, 8),    256, 0, stream>>>(X, Kin, Vpart);
  k_out   <<<dim3(4, 16, 8),     256, 0, stream>>>(Vpart, Kout, out);
}

// Round 2
// 136.138 us; speedup vs baseline: 1.0305x; 1.0305x over previous
//
#include <hip/hip_runtime.h>

// Problem constants (from reference):
//   X:          [8][512][4096] f32
//   gates:      [8][8]          f32
//   core_first: [8][1][8][8]    f32   (E, r=1, m0, p)
//   cores_mid:  [6][8][8][8][8] f32   (i, E, r, m, p)
//   core_last:  [8][8][8][1]    f32   (E, r, n3, 1)
//   out:        [8][512][4096]  f32
//
// Math: per batch b, out[b] = (X[b] · K_in[b]) · K_out[b]  (rank-8 factorized map)
//   K_in  [8][4096][8]  composed from gate-merged input cores
//   K_out [8][8][4096]  composed from gate-merged output cores

#define MC_ 8            // m-slices for the V reduction (512 m each)

__global__ __launch_bounds__(256) void k_compose(
    const float* __restrict__ gates,
    const float* __restrict__ core_first,
    const float* __restrict__ cores_mid,
    const float* __restrict__ core_last,
    float* __restrict__ Kin,   // [8][4096][8]
    float* __restrict__ Kout)  // [8][8][4096]
{
  const int part = blockIdx.x;   // 0..7 : m3 slice for Kin, n0 slice for Kout
  const int b    = blockIdx.y;
  const int t    = threadIdx.x;

  __shared__ float g[8];
  __shared__ float mg[3200];                     // merged cores
  __shared__ __align__(16) float A2[512];        // [(m1,m0)][p2]
  __shared__ __align__(16) float A3[4096];       // [(m2,m1,m0)][p3]
  __shared__ __align__(16) float C2[512];        // [p6][(n2,n3)]
  __shared__ __align__(16) float C3[4096];       // [p5][(n1,n2,n3)]

  if (t < 8) g[t] = gates[b*8 + t];
  __syncthreads();

  for (int idx = t; idx < 3200; idx += 256) {
    float acc = 0.f;
    if (idx < 64) {
      #pragma unroll
      for (int e = 0; e < 8; ++e) acc += g[e] * core_first[e*64 + idx];
    } else if (idx < 3136) {
      const int i = (idx - 64) >> 9;
      const int w = (idx - 64) & 511;
      #pragma unroll
      for (int e = 0; e < 8; ++e) acc += g[e] * cores_mid[(i*8 + e)*512 + w];
    } else {
      const int w = idx - 3136;
      #pragma unroll
      for (int e = 0; e < 8; ++e) acc += g[e] * core_last[e*64 + w];
    }
    mg[idx] = acc;
  }
  __syncthreads();

  const float* mg0 = mg;
  const float* mg1 = mg + 64;
  const float* mg2 = mg + 64 + 512;
  const float* mg3 = mg + 64 + 1024;
  const float* mg4 = mg + 64 + 1536;
  const float* mg5 = mg + 64 + 2048;
  const float* mg6 = mg + 64 + 2560;
  const float* mg7 = mg + 3136;

  for (int idx = t; idx < 1024; idx += 256) {
    if (idx < 512) {
      const int mm = idx >> 3, p2 = idx & 7;
      const int m1 = mm >> 3, m0 = mm & 7;
      float acc = 0.f;
      #pragma unroll
      for (int p1 = 0; p1 < 8; ++p1)
        acc += mg0[m0*8 + p1] * mg1[p1*64 + m1*8 + p2];
      A2[idx] = acc;
    } else {
      const int id = idx - 512;
      const int p6 = id >> 6, n2 = (id >> 3) & 7, n3 = id & 7;
      float acc = 0.f;
      #pragma unroll
      for (int p7 = 0; p7 < 8; ++p7)
        acc += mg6[p6*64 + n2*8 + p7] * mg7[p7*8 + n3];
      C2[id] = acc;
    }
  }
  __syncthreads();

  for (int idx = t; idx < 8192; idx += 256) {
    if (idx < 4096) {
      const int rest = idx >> 3, p3 = idx & 7;
      const int m2 = rest >> 6, mm = rest & 63;
      float acc = 0.f;
      #pragma unroll
      for (int p2 = 0; p2 < 8; ++p2)
        acc += A2[mm*8 + p2] * mg2[p2*64 + m2*8 + p3];
      A3[idx] = acc;
    } else {
      const int id = idx - 4096;
      const int p5 = id >> 9, n1 = (id >> 6) & 7, nn = id & 63;
      float acc = 0.f;
      #pragma unroll
      for (int p6 = 0; p6 < 8; ++p6)
        acc += mg5[p5*64 + n1*8 + p6] * C2[p6*64 + nn];
      C3[id] = acc;
    }
  }
  __syncthreads();

  {
    float* kb = Kin + b*32768 + part*4096;
    #pragma unroll
    for (int rr = 0; rr < 2; ++rr) {
      const int r = t*2 + rr;
      #pragma unroll
      for (int p4 = 0; p4 < 8; ++p4) {
        float acc = 0.f;
        #pragma unroll
        for (int p3 = 0; p3 < 8; ++p3)
          acc += A3[r*8 + p3] * mg3[p3*64 + part*8 + p4];
        kb[r*8 + p4] = acc;
      }
    }
    float* ob = Kout + b*32768 + part*512;
    #pragma unroll
    for (int jj = 0; jj < 2; ++jj) {
      const int j = t*2 + jj;
      #pragma unroll
      for (int p4 = 0; p4 < 8; ++p4) {
        float acc = 0.f;
        #pragma unroll
        for (int p5 = 0; p5 < 8; ++p5)
          acc += mg4[p4*64 + part*8 + p5] * C3[p5*512 + j];
        ob[p4*4096 + j] = acc;
      }
    }
  }
}

// V partials, LDS-staged so every global access is wave-coalesced.
// Block = (stile of 16 s-rows) x (m-slice of 512).  256 threads.
// Vpart[b][mc][s][p] = sum_{m in slice mc} X[b][s][m] * Kin[b][m][p]
#define XPAD 516   // 512 + 4 floats: bank stride 4, keeps float4 alignment

__global__ __launch_bounds__(256) void k_vpart(
    const float* __restrict__ X,
    const float* __restrict__ Kin,
    float* __restrict__ Vpart)
{
  const int stile = blockIdx.x;   // 0..31 (16 rows each)
  const int mc    = blockIdx.y;   // 0..7  (512 m each)
  const int b     = blockIdx.z;   // 0..7
  const int t     = threadIdx.x;

  __shared__ __align__(16) float xs[16 * XPAD];    // 33.0 KB
  __shared__ __align__(16) float lkT[8 * XPAD];    // 16.5 KB, K chunk transposed [p][m]
  __shared__ float vred[2 * 16 * 8];               // 1 KB

  // --- Stage X tile [16][512], coalesced: lanes read consecutive float4s ---
  {
    const float* xbase = X + ((size_t)(b*512 + stile*16) * 4096) + mc*512;
    #pragma unroll
    for (int i = 0; i < 8; ++i) {
      const int idx = t + i*256;          // 2048 float4 total
      const int r = idx >> 7;             // 128 float4 per row
      const int c = idx & 127;
      const float4 v = ((const float4*)(xbase + (size_t)r*4096))[c];
      *(float4*)&xs[r*XPAD + c*4] = v;
    }
  }
  // --- Stage K_in chunk [512][8] -> transposed lkT[p][m] ---
  {
    const float4* kb = (const float4*)(Kin + b*32768 + mc*4096);  // 1024 float4
    #pragma unroll
    for (int i = 0; i < 4; ++i) {
      const int idx = t + i*256;
      const int m  = idx >> 1;
      const int ph = (idx & 1) * 4;
      const float4 v = kb[idx];
      lkT[(ph+0)*XPAD + m] = v.x;
      lkT[(ph+1)*XPAD + m] = v.y;
      lkT[(ph+2)*XPAD + m] = v.z;
      lkT[(ph+3)*XPAD + m] = v.w;
    }
  }
  __syncthreads();

  // --- Compute: thread owns (s_local, p) for half the m-range ---
  {
    const int h  = t >> 7;        // m-half
    const int sp = t & 127;
    const int sl = sp >> 3;
    const int p  = sp & 7;
    const float* xrow = &xs[sl*XPAD + h*256];
    const float* krow = &lkT[p*XPAD + h*256];
    float acc = 0.f;
    #pragma unroll 8
    for (int j = 0; j < 64; ++j) {
      const float4 a = *(const float4*)(xrow + j*4);
      const float4 k = *(const float4*)(krow + j*4);
      acc += a.x*k.x + a.y*k.y + a.z*k.z + a.w*k.w;
    }
    vred[t] = acc;   // vred[h][sl][p]
  }
  __syncthreads();

  if (t < 128) {
    const float v = vred[t] + vred[128 + t];
    Vpart[((size_t)(b*MC_ + mc)*512 + stile*16)*8 + t] = v;   // [..][sl][p], coalesced
  }
}

// out[b][s][n] = sum_p (sum_mc Vpart[b][mc][s][p]) * Kout[b][p][n]
__global__ __launch_bounds__(256) void k_out(
    const float* __restrict__ Vpart,
    const float* __restrict__ Kout,
    float* __restrict__ Out)
{
  const int nc = blockIdx.x;   // 0..3   (1024 n each)
  const int sg = blockIdx.y;   // 0..15  (32 s each)
  const int b  = blockIdx.z;   // 0..7
  const int t  = threadIdx.x;

  __shared__ __align__(16) float vs[32*8];

  // Sum the MC_ m-slice partials for this block's 32 s.  t == s_local*8 + p.
  {
    const float* vp = Vpart + ((size_t)b*MC_*512 + sg*32)*8 + t;
    float a = 0.f;
    #pragma unroll
    for (int mc = 0; mc < MC_; ++mc) a += vp[(size_t)mc*512*8];
    vs[t] = a;
  }

  float4 kr[8];
  {
    const float* kb = Kout + b*32768 + nc*1024 + t*4;
    #pragma unroll
    for (int p = 0; p < 8; ++p) kr[p] = *(const float4*)(kb + p*4096);
  }
  __syncthreads();

  float* ob = Out + (size_t)(b*512 + sg*32)*4096 + nc*1024 + t*4;
  for (int s = 0; s < 32; ++s) {
    const float* vv = &vs[s*8];
    float o0 = 0.f, o1 = 0.f, o2 = 0.f, o3 = 0.f;
    #pragma unroll
    for (int p = 0; p < 8; ++p) {
      const float v = vv[p];
      o0 += v * kr[p].x; o1 += v * kr[p].y; o2 += v * kr[p].z; o3 += v * kr[p].w;
    }
    *(float4*)(ob + (size_t)s*4096) = make_float4(o0, o1, o2, o3);
  }
}

extern "C" void kernel_launch(void* const* d_in, const int* in_sizes, int n_in,
                              void* d_out, int out_size, void* d_ws, size_t ws_size,
                              hipStream_t stream) {
  const float* X     = (const float*)d_in[0];
  const float* gates = (const float*)d_in[1];
  const float* cf    = (const float*)d_in[2];
  const float* cm    = (const float*)d_in[3];
  const float* cl    = (const float*)d_in[4];
  float* out = (float*)d_out;

  float* ws    = (float*)d_ws;
  float* Kin   = ws;                 // 262144 floats (1 MB)
  float* Kout  = ws + 262144;        // 262144 floats (1 MB)
  float* Vpart = ws + 524288;        // 262144 floats (1 MB)

  k_compose<<<dim3(8, 8),          256, 0, stream>>>(gates, cf, cm, cl, Kin, Kout);
  k_vpart <<<dim3(32, MC_, 8),     256, 0, stream>>>(X, Kin, Vpart);
  k_out   <<<dim3(4, 16, 8),       256, 0, stream>>>(Vpart, Kout, out);
}